// Round 4
// baseline (349.103 us; speedup 1.0000x reference)
//
#include <hip/hip_runtime.h>
#include <stdint.h>

typedef _Float16 f16;
typedef _Float16 half8 __attribute__((ext_vector_type(8)));
typedef _Float16 half4 __attribute__((ext_vector_type(4)));
typedef float floatx16 __attribute__((ext_vector_type(16)));

#define NIMG 3072

// ws byte offsets (all 16B-aligned)
#define WS_W0T   0           // f16 [5ky][2ch][2hf][32co][8j]            = 5,120
#define WS_W1T   10240       // f16 [25tap][2ch][2hf][32co][8j]          = 25,600
#define WS_W2T   61440       // f16 [16tap][2ch][2ct][2hf][32co][8j]     = 32,768
#define WS_W3T   126976      // f16 [36c][2ct][2hf][32col][8j]           = 36,864
#define WS_FC1T  200704      // f16 [6l][16c][4nt][2hf][32][8]           = 196,608
#define WS_FC2T  593920      // f16 [6l][8c][2nt][2hf][32][8]            = 49,152
#define WS_FC3T  692224      // f16 [6l][4c][2hf][32][8]                 = 12,288
#define WS_BIG   720896      // fused: h2g f16 3072*2592 | split: h1 f16 3072*14112
#define H1_BYTES 86704128ull
#define WS_H3F_FUSED 16646144ull
#define WS_H3F_SPLIT (720896ull + 86704128ull)              // 87,425,024
#define NEED_SPLIT   (WS_H3F_SPLIT + 6291456ull)            // 93,716,480

#define Z16 {0.f,0.f,0.f,0.f,0.f,0.f,0.f,0.f,0.f,0.f,0.f,0.f,0.f,0.f,0.f,0.f}

// ---------------- weight transform ----------------
__global__ __launch_bounds__(256) void k_prep(
    const float* __restrict__ w0, const float* __restrict__ w1, const float* __restrict__ w2,
    const float* __restrict__ w3, const float* __restrict__ fc1w, const float* __restrict__ fc2w,
    const float* __restrict__ fc3w,
    f16* __restrict__ w0t, f16* __restrict__ w1t, f16* __restrict__ w2t, f16* __restrict__ w3t,
    f16* __restrict__ fc1t, f16* __restrict__ fc2t, f16* __restrict__ fc3t)
{
  int stride = gridDim.x * blockDim.x;
  int g0 = blockIdx.x * blockDim.x + threadIdx.x;
  for (int i = g0; i < 5120; i += stride) {
    int j = i & 7, co = (i >> 3) & 31, hf = (i >> 8) & 1, ch = (i >> 9) & 1, ky = i >> 10;
    int k = ch * 16 + hf * 8 + j;
    f16 v = (f16)0.f;
    if (k < 20) { int kx = k >> 2, ci = k & 3; v = (f16)w0[((co * 4 + ci) * 5 + ky) * 5 + kx]; }
    w0t[i] = v;
  }
  for (int i = g0; i < 25600; i += stride) {
    int j = i & 7, co = (i >> 3) & 31, hf = (i >> 8) & 1, ch = (i >> 9) & 1, tap = i >> 10;
    int ci = ch * 16 + hf * 8 + j, ky = tap / 5, kx = tap % 5;
    w1t[i] = (f16)w1[((co * 32 + ci) * 5 + ky) * 5 + kx];
  }
  for (int i = g0; i < 32768; i += stride) {
    int j = i & 7, co = (i >> 3) & 31, hf = (i >> 8) & 1, ct = (i >> 9) & 1, ch = (i >> 10) & 1, tap = i >> 11;
    int ci = ch * 16 + hf * 8 + j, cog = ct * 32 + co, ky = tap >> 2, kx = tap & 3;
    w2t[i] = (f16)w2[((cog * 32 + ci) * 4 + ky) * 4 + kx];
  }
  for (int i = g0; i < 36864; i += stride) {
    int j = i & 7, col = (i >> 3) & 31, hf = (i >> 8) & 1, ct = (i >> 9) & 1, c = i >> 10;
    int k = c * 16 + hf * 8 + j, tap = k >> 6, ci = k & 63, co = ct * 32 + col;
    int ky = tap / 3, kx = tap % 3;
    w3t[i] = (f16)w3[((co * 64 + ci) * 3 + ky) * 3 + kx];
  }
  for (int i = g0; i < 196608; i += stride) {
    int j = i & 7, col = (i >> 3) & 31, hf = (i >> 8) & 1, nt = (i >> 9) & 3, c = (i >> 11) & 15, l = i >> 15;
    int k = c * 16 + hf * 8 + j, o = nt * 32 + col;
    fc1t[i] = (f16)fc1w[(l * 256 + k) * 128 + o];
  }
  for (int i = g0; i < 49152; i += stride) {
    int j = i & 7, col = (i >> 3) & 31, hf = (i >> 8) & 1, nt = (i >> 9) & 1, c = (i >> 10) & 7, l = i >> 13;
    int k = c * 16 + hf * 8 + j, o = nt * 32 + col;
    fc2t[i] = (f16)fc2w[(l * 128 + k) * 64 + o];
  }
  for (int i = g0; i < 12288; i += stride) {
    int j = i & 7, col = (i >> 3) & 31, hf = (i >> 8) & 1, c = (i >> 9) & 3, l = i >> 11;
    int k = c * 16 + hf * 8 + j;
    f16 v = (f16)0.f;
    if (col < 4) v = (f16)fc3w[(l * 64 + k) * 4 + col];
    fc3t[i] = v;
  }
}

// ================= SPLIT PATH =================
// conv0+pool: x (4,45,45) f32 -> h1 (21*21, 32) f16 NHWC at n*14112
__global__ __launch_bounds__(256, 6) void k_conv0(
    const float* __restrict__ x,
    const f16* __restrict__ w0t, const float* __restrict__ b0, const float* __restrict__ a0p,
    f16* __restrict__ h1g)
{
  __shared__ __align__(16) uint32_t s_u[5264];   // [47][56][4] f16 = 21,056 B
  f16* s_x = (f16*)s_u;
  const int n = blockIdx.x, tid = threadIdx.x;
  const int wv = tid >> 6, l = tid & 63;
  const int hf = l >> 5, m = l & 31, dr = m >> 3, dc = m & 7, col = m;
  const float a0 = a0p[0];
  const float b0c = b0[col];
  const half8* w0t8 = (const half8*)w0t;

  for (int i = tid; i < 5264; i += 256) s_u[i] = 0u;
  __syncthreads();
  const float* xin = x + n * 8100;
  for (int i = tid; i < 8100; i += 256) {
    int ci = i / 2025, r = i % 2025;
    int y = r / 45, xx = r % 45;
    s_x[((y + 1) * 56 + (xx + 1)) * 4 + ci] = (f16)xin[i];
  }
  __syncthreads();

  half8 B0[5][2];
  #pragma unroll
  for (int ky = 0; ky < 5; ++ky)
    #pragma unroll
    for (int ch = 0; ch < 2; ++ch)
      B0[ky][ch] = w0t8[(ky * 2 + ch) * 64 + hf * 32 + col];

  const int r0lut0[11] = {0,4,8,12,16,20,24,28,32,36,38};
  f16* outb = h1g + n * 14112;
  for (int t = wv; t < 66; t += 4) {
    int r0 = r0lut0[t / 6], cb = (t % 6) * 8;
    int rowb = r0 + dr, colb = cb + dc;
    const f16* pA = s_x + (rowb * 56 + colb + 2 * hf) * 4;
    floatx16 acc = Z16;
    #pragma unroll
    for (int ky = 0; ky < 5; ++ky) {
      const f16* p = pA + ky * 224;
      half4 l0  = *(const half4*)(p);
      half4 h0  = *(const half4*)(p + 4);
      half4 l1  = *(const half4*)(p + 16);
      half4 h1v = *(const half4*)(p + 20);
      half8 a0v = __builtin_shufflevector(l0, h0, 0,1,2,3,4,5,6,7);
      half8 a1v = __builtin_shufflevector(l1, h1v, 0,1,2,3,4,5,6,7);
      acc = __builtin_amdgcn_mfma_f32_32x32x16_f16(a0v, B0[ky][0], acc, 0, 0, 0);
      acc = __builtin_amdgcn_mfma_f32_32x32x16_f16(a1v, B0[ky][1], acc, 0, 0, 0);
    }
    #pragma unroll
    for (int pp = 0; pp < 2; ++pp)
      #pragma unroll
      for (int c2 = 0; c2 < 2; ++c2) {
        float mm = fmaxf(fmaxf(acc[8*pp + 2*c2], acc[8*pp + 2*c2 + 1]),
                         fmaxf(acc[8*pp + 4 + 2*c2], acc[8*pp + 4 + 2*c2 + 1]));
        mm += b0c;
        float v = fmaxf(mm, 0.f) + a0 * fminf(mm, 0.f);
        int pr = (r0 >> 1) + pp, pc = (cb >> 1) + 2 * hf + c2;
        if (pc < 21) outb[(pr * 21 + pc) * 32 + col] = (f16)v;
      }
  }
}

// conv1+pool: h1 (21*21,32) f16 -> h2 (81,32) f16 written at h1 base + n*14112 (alias-safe)
__global__ __launch_bounds__(512, 6) void k_conv1(
    const f16* __restrict__ h1g,
    const f16* __restrict__ w1t, const float* __restrict__ b1, const float* __restrict__ a1p,
    f16* __restrict__ h2g, int h2stride)
{
  __shared__ __align__(16) uint32_t s_u[11440];  // [22][26][40] f16 = 45,760 B
  f16* s_h1 = (f16*)s_u;
  const int n = blockIdx.x, tid = threadIdx.x;
  const int wv = tid >> 6, l = tid & 63;
  const int hf = l >> 5, m = l & 31, dr = m >> 3, dc = m & 7, col = m;
  const float a1 = a1p[0];
  const float b1c = b1[col];
  const half8* w1t8 = (const half8*)w1t;

  for (int i = tid; i < 11440; i += 512) s_u[i] = 0u;
  __syncthreads();
  const f16* inb = h1g + n * 14112;
  for (int i = tid; i < 1764; i += 512) {
    int pos = i >> 2, part = i & 3;
    int r = pos / 21, c = pos % 21;
    *(half8*)(s_h1 + ((r + 1) * 26 + (c + 1)) * 40 + part * 8) =
      *(const half8*)(inb + pos * 32 + part * 8);
  }
  __syncthreads();

  const int r0lut1[5] = {0, 4, 8, 12, 14};
  const int cclut[3]  = {0, 8, 14};
  int t0 = wv * 2;
  int t1 = t0 + 1; if (t1 > 14) t1 = 14;
  int r0a = r0lut1[t0 / 3], cca = cclut[t0 % 3];
  int r0b = r0lut1[t1 / 3], ccb = cclut[t1 % 3];
  const f16* pAa = s_h1 + ((r0a + dr) * 26 + cca + dc) * 40 + hf * 8;
  const f16* pAb = s_h1 + ((r0b + dr) * 26 + ccb + dc) * 40 + hf * 8;
  floatx16 accA = Z16;
  floatx16 accB = Z16;
  for (int ky = 0; ky < 5; ++ky) {
    const half8* wb = w1t8 + ky * 640 + hf * 32 + col;
    const f16* qa = pAa + ky * 1040;
    const f16* qb = pAb + ky * 1040;
    #pragma unroll
    for (int kx = 0; kx < 5; ++kx) {
      #pragma unroll
      for (int ch = 0; ch < 2; ++ch) {
        half8 b  = wb[kx * 128 + ch * 64];
        half8 aA = *(const half8*)(qa + kx * 40 + ch * 16);
        half8 aB = *(const half8*)(qb + kx * 40 + ch * 16);
        accA = __builtin_amdgcn_mfma_f32_32x32x16_f16(aA, b, accA, 0, 0, 0);
        accB = __builtin_amdgcn_mfma_f32_32x32x16_f16(aB, b, accB, 0, 0, 0);
      }
    }
  }
  __syncthreads();   // all reads of s_h1 (and h1g image n) done before h2 alias write
  f16* outp = h2g + n * h2stride;
  #pragma unroll
  for (int tt = 0; tt < 2; ++tt) {
    const floatx16 acc = tt ? accB : accA;
    int r0 = tt ? r0b : r0a, cc = tt ? ccb : cca;
    #pragma unroll
    for (int pp = 0; pp < 2; ++pp)
      #pragma unroll
      for (int c2 = 0; c2 < 2; ++c2) {
        float v = fmaxf(fmaxf(acc[8*pp + 2*c2], acc[8*pp + 2*c2 + 1]),
                        fmaxf(acc[8*pp + 4 + 2*c2], acc[8*pp + 4 + 2*c2 + 1]));
        v += b1c; v = (v >= 0.f) ? v : a1 * v;
        int pr = (r0 >> 1) + pp, pc = (cc >> 1) + 2 * hf + c2;
        if (pc < 9) outp[(pr * 9 + pc) * 32 + col] = (f16)v;
      }
  }
}

// ================= FUSED FALLBACK (verified round-2 kernel) =================
__global__ __launch_bounds__(512) void k_conv01(
    const float* __restrict__ x,
    const f16* __restrict__ w0t, const float* __restrict__ b0, const float* __restrict__ a0p,
    const f16* __restrict__ w1t, const float* __restrict__ b1, const float* __restrict__ a1p,
    f16* __restrict__ h2g)
{
  __shared__ __align__(16) uint32_t smem_u[16328];
  f16* sh   = (f16*)smem_u;
  f16* s_x  = sh;
  f16* s_h1 = sh + 9776;

  const int n = blockIdx.x, tid = threadIdx.x;
  const int wv = tid >> 6, l = tid & 63;
  const int hf = l >> 5, m = l & 31, dr = m >> 3, dc = m & 7, col = m;
  const float a0 = a0p[0], a1 = a1p[0];
  const float b0c = b0[col], b1c = b1[col];
  const half8* w0t8 = (const half8*)w0t;
  const half8* w1t8 = (const half8*)w1t;

  for (int i = tid; i < 16328; i += 512) smem_u[i] = 0u;
  __syncthreads();
  const float* xin = x + n * 8100;
  for (int i = tid; i < 8100; i += 512) {
    int ci = i / 2025, r = i % 2025;
    int y = r / 45, xx = r % 45;
    s_x[((y + 1) * 52 + (xx + 1)) * 4 + ci] = (f16)xin[i];
  }
  __syncthreads();

  half8 B0[5][2];
  #pragma unroll
  for (int ky = 0; ky < 5; ++ky)
    #pragma unroll
    for (int ch = 0; ch < 2; ++ch)
      B0[ky][ch] = w0t8[(ky * 2 + ch) * 64 + hf * 32 + col];

  const int r0lut0[11] = {0,4,8,12,16,20,24,28,32,36,38};
  for (int t = wv; t < 66; t += 8) {
    int r0 = r0lut0[t / 6], cb = (t % 6) * 8;
    int rowb = r0 + dr, colb = cb + dc;
    const f16* pA0 = s_x + (rowb * 52 + colb + 2 * hf) * 4;
    const f16* pA1 = s_x + (rowb * 52 + colb + 4) * 4;
    floatx16 acc = Z16;
    #pragma unroll
    for (int ky = 0; ky < 5; ++ky) {
      half4 lo = *(const half4*)(pA0 + ky * 208);
      half4 hi = *(const half4*)(pA0 + ky * 208 + 4);
      half8 a0v = __builtin_shufflevector(lo, hi, 0,1,2,3,4,5,6,7);
      acc = __builtin_amdgcn_mfma_f32_32x32x16_f16(a0v, B0[ky][0], acc, 0, 0, 0);
      half8 a1v = {(f16)0,(f16)0,(f16)0,(f16)0,(f16)0,(f16)0,(f16)0,(f16)0};
      if (hf == 0) {
        half4 l1 = *(const half4*)(pA1 + ky * 208);
        a1v[0] = l1[0]; a1v[1] = l1[1]; a1v[2] = l1[2]; a1v[3] = l1[3];
      }
      acc = __builtin_amdgcn_mfma_f32_32x32x16_f16(a1v, B0[ky][1], acc, 0, 0, 0);
    }
    #pragma unroll
    for (int pp = 0; pp < 2; ++pp)
      #pragma unroll
      for (int c2 = 0; c2 < 2; ++c2) {
        float v = fmaxf(fmaxf(acc[8*pp + 2*c2], acc[8*pp + 2*c2 + 1]),
                        fmaxf(acc[8*pp + 4 + 2*c2], acc[8*pp + 4 + 2*c2 + 1]));
        v += b0c; v = (v >= 0.f) ? v : a0 * v;
        int pr = (r0 >> 1) + pp, pc = (cb >> 1) + 2 * hf + c2;
        if (pc < 21) s_h1[((pr + 1) * 26 + (pc + 1)) * 40 + col] = (f16)v;
      }
  }
  __syncthreads();

  const int r0lut1[5] = {0, 4, 8, 12, 14};
  const int cclut[3]  = {0, 8, 14};
  int t0 = wv * 2;
  int t1 = t0 + 1; if (t1 > 14) t1 = 14;
  int r0a = r0lut1[t0 / 3], cca = cclut[t0 % 3];
  int r0b = r0lut1[t1 / 3], ccb = cclut[t1 % 3];
  const f16* pAa = s_h1 + ((r0a + dr) * 26 + cca + dc) * 40 + hf * 8;
  const f16* pAb = s_h1 + ((r0b + dr) * 26 + ccb + dc) * 40 + hf * 8;
  floatx16 accA = Z16;
  floatx16 accB = Z16;
  for (int ky = 0; ky < 5; ++ky) {
    const half8* wb = w1t8 + ky * 640 + hf * 32 + col;
    const f16* qa = pAa + ky * 1040;
    const f16* qb = pAb + ky * 1040;
    #pragma unroll
    for (int kx = 0; kx < 5; ++kx) {
      #pragma unroll
      for (int ch = 0; ch < 2; ++ch) {
        half8 b  = wb[kx * 128 + ch * 64];
        half8 aA = *(const half8*)(qa + kx * 40 + ch * 16);
        half8 aB = *(const half8*)(qb + kx * 40 + ch * 16);
        accA = __builtin_amdgcn_mfma_f32_32x32x16_f16(aA, b, accA, 0, 0, 0);
        accB = __builtin_amdgcn_mfma_f32_32x32x16_f16(aB, b, accB, 0, 0, 0);
      }
    }
  }
  f16* outp = h2g + n * 2592;
  #pragma unroll
  for (int tt = 0; tt < 2; ++tt) {
    const floatx16 acc = tt ? accB : accA;
    int r0 = tt ? r0b : r0a, cc = tt ? ccb : cca;
    #pragma unroll
    for (int pp = 0; pp < 2; ++pp)
      #pragma unroll
      for (int c2 = 0; c2 < 2; ++c2) {
        float v = fmaxf(fmaxf(acc[8*pp + 2*c2], acc[8*pp + 2*c2 + 1]),
                        fmaxf(acc[8*pp + 4 + 2*c2], acc[8*pp + 4 + 2*c2 + 1]));
        v += b1c; v = (v >= 0.f) ? v : a1 * v;
        int pr = (r0 >> 1) + pp, pc = (cc >> 1) + 2 * hf + c2;
        if (pc < 9) outp[(pr * 9 + pc) * 32 + col] = (f16)v;
      }
  }
}

// ---------------- conv2+pool (MFMA f16), 2 images per block ----------------
__global__ __launch_bounds__(256) void k_conv2(
    const f16* __restrict__ h2g, int h2stride, const f16* __restrict__ w2t,
    const float* __restrict__ b2, const float* __restrict__ a2p,
    f16* __restrict__ h3f)
{
  __shared__ __align__(16) uint32_t s_u[5760];
  f16* s2 = (f16*)s_u;
  const int n0 = blockIdx.x * 2, tid = threadIdx.x;
  const int wv = tid >> 6, l = tid & 63;
  const int hf = l >> 5, m = l & 31, dr = m >> 3, dc = m & 7, col = m;
  const int img = wv >> 1, ct = wv & 1;
  const float a2 = a2p[0];
  const float b2c = b2[ct * 32 + col];
  const half8* w2t8 = (const half8*)w2t;

  for (int i = tid; i < 5760; i += 256) s_u[i] = 0u;
  __syncthreads();
  for (int c = tid; c < 648; c += 256) {
    int im = c / 324, rr = c % 324, pos = rr >> 2, part = rr & 3;
    int r = pos / 9, cc = pos % 9;
    *(half8*)(s2 + im * 5760 + ((r + 1) * 12 + (cc + 1)) * 40 + part * 8) =
      *(const half8*)(h2g + (size_t)(n0 + im) * h2stride + pos * 32 + part * 8);
  }
  __syncthreads();

  const f16* sbase = s2 + img * 5760;
  const f16* pA0 = sbase + (dr * 12 + dc) * 40 + hf * 8;
  const f16* pA4 = sbase + ((4 + dr) * 12 + dc) * 40 + hf * 8;
  floatx16 acc0 = Z16;
  floatx16 acc4 = Z16;
  for (int tap = 0; tap < 16; ++tap) {
    int ky = tap >> 2, kx = tap & 3;
    int aoff = (ky * 12 + kx) * 40;
    #pragma unroll
    for (int ch = 0; ch < 2; ++ch) {
      half8 b  = w2t8[tap * 256 + ch * 128 + ct * 64 + hf * 32 + col];
      half8 a0 = *(const half8*)(pA0 + aoff + ch * 16);
      half8 a4 = *(const half8*)(pA4 + aoff + ch * 16);
      acc0 = __builtin_amdgcn_mfma_f32_32x32x16_f16(a0, b, acc0, 0, 0, 0);
      acc4 = __builtin_amdgcn_mfma_f32_32x32x16_f16(a4, b, acc4, 0, 0, 0);
    }
  }
  f16* o = h3f + (n0 + img) * 1024;
  #pragma unroll
  for (int tt = 0; tt < 2; ++tt) {
    const floatx16 acc = tt ? acc4 : acc0;
    #pragma unroll
    for (int pp = 0; pp < 2; ++pp)
      #pragma unroll
      for (int c2 = 0; c2 < 2; ++c2) {
        float v = fmaxf(fmaxf(acc[8*pp + 2*c2], acc[8*pp + 2*c2 + 1]),
                        fmaxf(acc[8*pp + 4 + 2*c2], acc[8*pp + 4 + 2*c2 + 1]));
        v += b2c; v = (v >= 0.f) ? v : a2 * v;
        int pr = tt * 2 + pp, pc = 2 * hf + c2, co = ct * 32 + col;
        o[(pr * 4 + pc) * 64 + co] = (f16)v;
      }
  }
}

// ---------------- fused conv3 + fc1 + fc2 + fc3 (MFMA f16) ----------------
__global__ __launch_bounds__(256) void k_tail(
    const f16* __restrict__ h3f,
    const f16* __restrict__ w3t, const float* __restrict__ b3, const float* __restrict__ a3p,
    const f16* __restrict__ fc1t, const float* __restrict__ fc1b, const float* __restrict__ a4,
    const f16* __restrict__ fc2t, const float* __restrict__ fc2b, const float* __restrict__ a5,
    const f16* __restrict__ fc3t, const float* __restrict__ fc3b,
    float* __restrict__ out)
{
  __shared__ __align__(16) f16 s_feat[32 * 264];
  __shared__ __align__(16) f16 s_g1[32 * 136];
  __shared__ __align__(16) f16 s_g2[32 * 72];

  const int lm = blockIdx.x % 6, t = blockIdx.x / 6;
  const int tid = threadIdx.x, wv = tid >> 6, lane = tid & 63;
  const int hf = lane >> 5, col = lane & 31;
  const half8* w3t8  = (const half8*)w3t;
  const half8* fc1t8 = (const half8*)fc1t;
  const half8* fc2t8 = (const half8*)fc2t;
  const half8* fc3t8 = (const half8*)fc3t;

  {
    const int mt = wv;
    const int i_img = mt * 8 + (col >> 2);
    const int pos = col & 3, oy = pos >> 1, ox = pos & 1;
    const int gimg = (t * 32 + i_img) * 6 + lm;
    const f16* Abase = h3f + gimg * 1024 + (oy * 4 + ox) * 64;
    floatx16 acc0 = Z16, acc1 = Z16;
    for (int c = 0; c < 36; ++c) {
      int tap = c >> 2;
      int ky = tap / 3, kx = tap % 3;
      half8 a = *(const half8*)(Abase + (ky * 4 + kx) * 64 + (c & 3) * 16 + hf * 8);
      half8 bb0 = w3t8[((c * 2 + 0) * 2 + hf) * 32 + col];
      half8 bb1 = w3t8[((c * 2 + 1) * 2 + hf) * 32 + col];
      acc0 = __builtin_amdgcn_mfma_f32_32x32x16_f16(a, bb0, acc0, 0, 0, 0);
      acc1 = __builtin_amdgcn_mfma_f32_32x32x16_f16(a, bb1, acc1, 0, 0, 0);
    }
    const float a3 = a3p[0];
    #pragma unroll
    for (int ct = 0; ct < 2; ++ct) {
      const floatx16 acc = ct ? acc1 : acc0;
      const int co = ct * 32 + col;
      const float bb = b3[co];
      #pragma unroll
      for (int q = 0; q < 4; ++q) {
        int ii = mt * 8 + 2 * q + hf;
        half4 w;
        #pragma unroll
        for (int z = 0; z < 4; ++z) {
          float v = acc[q * 4 + z] + bb;
          v = (v >= 0.f) ? v : a3 * v;
          w[z] = (f16)v;
        }
        *(half4*)(s_feat + ii * 264 + co * 4) = w;
      }
    }
  }
  __syncthreads();

  {
    floatx16 g = Z16;
    for (int c = 0; c < 16; ++c) {
      half8 a = *(const half8*)(s_feat + col * 264 + c * 16 + hf * 8);
      half8 b = fc1t8[(((lm * 16 + c) * 4 + wv) * 2 + hf) * 32 + col];
      g = __builtin_amdgcn_mfma_f32_32x32x16_f16(a, b, g, 0, 0, 0);
    }
    const float a4v = a4[lm];
    const float bb = fc1b[lm * 128 + wv * 32 + col];
    #pragma unroll
    for (int reg = 0; reg < 16; ++reg) {
      int r = (reg & 3) + 8 * (reg >> 2) + 4 * hf;
      float v = g[reg] + bb;
      v = (v >= 0.f) ? v : a4v * v;
      s_g1[r * 136 + wv * 32 + col] = (f16)v;
    }
  }
  __syncthreads();

  if (wv < 2) {
    floatx16 g = Z16;
    for (int c = 0; c < 8; ++c) {
      half8 a = *(const half8*)(s_g1 + col * 136 + c * 16 + hf * 8);
      half8 b = fc2t8[(((lm * 8 + c) * 2 + wv) * 2 + hf) * 32 + col];
      g = __builtin_amdgcn_mfma_f32_32x32x16_f16(a, b, g, 0, 0, 0);
    }
    const float a5v = a5[lm];
    const float bb = fc2b[lm * 64 + wv * 32 + col];
    #pragma unroll
    for (int reg = 0; reg < 16; ++reg) {
      int r = (reg & 3) + 8 * (reg >> 2) + 4 * hf;
      float v = g[reg] + bb;
      v = (v >= 0.f) ? v : a5v * v;
      s_g2[r * 72 + wv * 32 + col] = (f16)v;
    }
  }
  __syncthreads();

  if (wv == 0) {
    floatx16 g = Z16;
    for (int c = 0; c < 4; ++c) {
      half8 a = *(const half8*)(s_g2 + col * 72 + c * 16 + hf * 8);
      half8 b = fc3t8[((lm * 4 + c) * 2 + hf) * 32 + col];
      g = __builtin_amdgcn_mfma_f32_32x32x16_f16(a, b, g, 0, 0, 0);
    }
    if (col < 4) {
      const float bb = fc3b[lm * 4 + col];
      #pragma unroll
      for (int reg = 0; reg < 16; ++reg) {
        int r = (reg & 3) + 8 * (reg >> 2) + 4 * hf;
        out[((t * 32 + r) * 6 + lm) * 4 + col] = g[reg] + bb;
      }
    }
  }
}

extern "C" void kernel_launch(void* const* d_in, const int* in_sizes, int n_in,
                              void* d_out, int out_size, void* d_ws, size_t ws_size,
                              hipStream_t stream) {
  const float* x    = (const float*)d_in[0];
  const float* w0   = (const float*)d_in[1];
  const float* b0   = (const float*)d_in[2];
  const float* w1   = (const float*)d_in[3];
  const float* b1   = (const float*)d_in[4];
  const float* w2   = (const float*)d_in[5];
  const float* b2   = (const float*)d_in[6];
  const float* w3   = (const float*)d_in[7];
  const float* b3   = (const float*)d_in[8];
  const float* a0   = (const float*)d_in[9];
  const float* a1   = (const float*)d_in[10];
  const float* a2   = (const float*)d_in[11];
  const float* a3   = (const float*)d_in[12];
  const float* fc1w = (const float*)d_in[13];
  const float* fc1b = (const float*)d_in[14];
  const float* a4   = (const float*)d_in[15];
  const float* fc2w = (const float*)d_in[16];
  const float* fc2b = (const float*)d_in[17];
  const float* a5   = (const float*)d_in[18];
  const float* fc3w = (const float*)d_in[19];
  const float* fc3b = (const float*)d_in[20];
  float* out = (float*)d_out;

  char* ws = (char*)d_ws;
  f16* w0t  = (f16*)(ws + WS_W0T);
  f16* w1t  = (f16*)(ws + WS_W1T);
  f16* w2t  = (f16*)(ws + WS_W2T);
  f16* w3t  = (f16*)(ws + WS_W3T);
  f16* fc1t = (f16*)(ws + WS_FC1T);
  f16* fc2t = (f16*)(ws + WS_FC2T);
  f16* fc3t = (f16*)(ws + WS_FC3T);

  k_prep<<<128, 256, 0, stream>>>(w0, w1, w2, w3, fc1w, fc2w, fc3w,
                                  w0t, w1t, w2t, w3t, fc1t, fc2t, fc3t);

  if (ws_size >= NEED_SPLIT) {
    f16* h1  = (f16*)(ws + WS_BIG);            // 3072 * 14112 f16
    f16* h3f = (f16*)(ws + WS_H3F_SPLIT);
    k_conv0<<<NIMG, 256, 0, stream>>>(x, w0t, b0, a0, h1);
    k_conv1<<<NIMG, 512, 0, stream>>>(h1, w1t, b1, a1, h1, 14112);  // h2 aliases own slot
    k_conv2<<<NIMG/2, 256, 0, stream>>>(h1, 14112, w2t, b2, a2, h3f);
    k_tail <<<96, 256, 0, stream>>>(h3f, w3t, b3, a3, fc1t, fc1b, a4,
                                    fc2t, fc2b, a5, fc3t, fc3b, out);
  } else {
    f16* h2g = (f16*)(ws + WS_BIG);
    f16* h3f = (f16*)(ws + WS_H3F_FUSED);
    k_conv01<<<NIMG, 512, 0, stream>>>(x, w0t, b0, a0, w1t, b1, a1, h2g);
    k_conv2 <<<NIMG/2, 256, 0, stream>>>(h2g, 2592, w2t, b2, a2, h3f);
    k_tail  <<<96, 256, 0, stream>>>(h3f, w3t, b3, a3, fc1t, fc1b, a4,
                                     fc2t, fc2b, a5, fc3t, fc3b, out);
  }
}

// Round 5
// 338.863 us; speedup vs baseline: 1.0302x; 1.0302x over previous
//
#include <hip/hip_runtime.h>
#include <stdint.h>

typedef _Float16 f16;
typedef _Float16 half8 __attribute__((ext_vector_type(8)));
typedef _Float16 half4 __attribute__((ext_vector_type(4)));
typedef float floatx16 __attribute__((ext_vector_type(16)));

#define NIMG 3072

// ws byte offsets (all 16B-aligned)
#define WS_W0T   0           // f16 [5ky][2ch][2hf][32co][8j]            = 5,120
#define WS_W1T   10240       // f16 [25tap][2ch][2hf][32co][8j]          = 25,600
#define WS_W2T   61440       // f16 [16tap][2ch][2ct][2hf][32co][8j]     = 32,768
#define WS_W3T   126976      // f16 [36c][2ct][2hf][32col][8j]           = 36,864
#define WS_FC1T  200704      // f16 [6l][16c][4nt][2hf][32][8]           = 196,608
#define WS_FC2T  593920      // f16 [6l][8c][2nt][2hf][32][8]            = 49,152
#define WS_FC3T  692224      // f16 [6l][4c][2hf][32][8]                 = 12,288
#define WS_H3F   720896      // f16 3072*1024, NHWC [16pos][64ci]        = 6,291,456

#define Z16 {0.f,0.f,0.f,0.f,0.f,0.f,0.f,0.f,0.f,0.f,0.f,0.f,0.f,0.f,0.f,0.f}

// ---------------- weight transform ----------------
__global__ __launch_bounds__(256) void k_prep(
    const float* __restrict__ w0, const float* __restrict__ w1, const float* __restrict__ w2,
    const float* __restrict__ w3, const float* __restrict__ fc1w, const float* __restrict__ fc2w,
    const float* __restrict__ fc3w,
    f16* __restrict__ w0t, f16* __restrict__ w1t, f16* __restrict__ w2t, f16* __restrict__ w3t,
    f16* __restrict__ fc1t, f16* __restrict__ fc2t, f16* __restrict__ fc3t)
{
  int stride = gridDim.x * blockDim.x;
  int g0 = blockIdx.x * blockDim.x + threadIdx.x;
  for (int i = g0; i < 5120; i += stride) {
    int j = i & 7, co = (i >> 3) & 31, hf = (i >> 8) & 1, ch = (i >> 9) & 1, ky = i >> 10;
    int k = ch * 16 + hf * 8 + j;
    f16 v = (f16)0.f;
    if (k < 20) { int kx = k >> 2, ci = k & 3; v = (f16)w0[((co * 4 + ci) * 5 + ky) * 5 + kx]; }
    w0t[i] = v;
  }
  for (int i = g0; i < 25600; i += stride) {
    int j = i & 7, co = (i >> 3) & 31, hf = (i >> 8) & 1, ch = (i >> 9) & 1, tap = i >> 10;
    int ci = ch * 16 + hf * 8 + j, ky = tap / 5, kx = tap % 5;
    w1t[i] = (f16)w1[((co * 32 + ci) * 5 + ky) * 5 + kx];
  }
  for (int i = g0; i < 32768; i += stride) {
    int j = i & 7, co = (i >> 3) & 31, hf = (i >> 8) & 1, ct = (i >> 9) & 1, ch = (i >> 10) & 1, tap = i >> 11;
    int ci = ch * 16 + hf * 8 + j, cog = ct * 32 + co, ky = tap >> 2, kx = tap & 3;
    w2t[i] = (f16)w2[((cog * 32 + ci) * 4 + ky) * 4 + kx];
  }
  for (int i = g0; i < 36864; i += stride) {
    int j = i & 7, col = (i >> 3) & 31, hf = (i >> 8) & 1, ct = (i >> 9) & 1, c = i >> 10;
    int k = c * 16 + hf * 8 + j, tap = k >> 6, ci = k & 63, co = ct * 32 + col;
    int ky = tap / 3, kx = tap % 3;
    w3t[i] = (f16)w3[((co * 64 + ci) * 3 + ky) * 3 + kx];
  }
  for (int i = g0; i < 196608; i += stride) {
    int j = i & 7, col = (i >> 3) & 31, hf = (i >> 8) & 1, nt = (i >> 9) & 3, c = (i >> 11) & 15, l = i >> 15;
    int k = c * 16 + hf * 8 + j, o = nt * 32 + col;
    fc1t[i] = (f16)fc1w[(l * 256 + k) * 128 + o];
  }
  for (int i = g0; i < 49152; i += stride) {
    int j = i & 7, col = (i >> 3) & 31, hf = (i >> 8) & 1, nt = (i >> 9) & 1, c = (i >> 10) & 7, l = i >> 13;
    int k = c * 16 + hf * 8 + j, o = nt * 32 + col;
    fc2t[i] = (f16)fc2w[(l * 128 + k) * 64 + o];
  }
  for (int i = g0; i < 12288; i += stride) {
    int j = i & 7, col = (i >> 3) & 31, hf = (i >> 8) & 1, c = (i >> 9) & 3, l = i >> 11;
    int k = c * 16 + hf * 8 + j;
    f16 v = (f16)0.f;
    if (col < 4) v = (f16)fc3w[(l * 64 + k) * 4 + col];
    fc3t[i] = v;
  }
}

// ---- fused conv0+pool + conv1+pool + conv2+pool (MFMA f16), one image/block ----
// x:(4,45,45)f32 -> h3f:(16pos,64co)f16 NHWC
__global__ __launch_bounds__(512) void k_conv012(
    const float* __restrict__ x,
    const f16* __restrict__ w0t, const float* __restrict__ b0, const float* __restrict__ a0p,
    const f16* __restrict__ w1t, const float* __restrict__ b1, const float* __restrict__ a1p,
    const f16* __restrict__ w2t, const float* __restrict__ b2, const float* __restrict__ a2p,
    f16* __restrict__ h3f)
{
  __shared__ __align__(16) uint32_t smem_u[16704];   // 66,816 B
  f16* sh   = (f16*)smem_u;
  f16* s_x  = sh;            // [47][56][4] = 10,528 f16 (input, +1 shift, zero pad)
  f16* s_h1 = sh + 10528;    // [22][26][40] = 22,880 f16 (h1 NHWC, +1 shift)
  f16* s_h2 = sh;            // [12][12][40] = 5,760 f16, aliases s_x (dead after conv0)

  const int n = blockIdx.x, tid = threadIdx.x;
  const int wv = tid >> 6, l = tid & 63;
  const int hf = l >> 5, m = l & 31, dr = m >> 3, dc = m & 7, col = m;
  const float a0 = a0p[0], a1 = a1p[0];
  const float b0c = b0[col], b1c = b1[col];
  const half8* w0t8 = (const half8*)w0t;
  const half8* w1t8 = (const half8*)w1t;
  const half8* w2t8 = (const half8*)w2t;

  for (int i = tid; i < 16704; i += 512) smem_u[i] = 0u;
  __syncthreads();
  const float* xin = x + n * 8100;
  for (int i = tid; i < 8100; i += 512) {
    int ci = i / 2025, r = i % 2025;
    int y = r / 45, xx = r % 45;
    s_x[((y + 1) * 56 + (xx + 1)) * 4 + ci] = (f16)xin[i];
  }
  __syncthreads();

  // ---- conv0: K per ky = 32 (2 chunks of 16; kx>=5 weights are zero); B resident ----
  half8 B0[5][2];
  #pragma unroll
  for (int ky = 0; ky < 5; ++ky)
    #pragma unroll
    for (int ch = 0; ch < 2; ++ch)
      B0[ky][ch] = w0t8[(ky * 2 + ch) * 64 + hf * 32 + col];

  const int r0lut0[11] = {0,4,8,12,16,20,24,28,32,36,38};
  for (int t = wv; t < 66; t += 8) {
    int r0 = r0lut0[t / 6], cb = (t % 6) * 8;
    int rowb = r0 + dr, colb = cb + dc;
    const f16* pA = s_x + (rowb * 56 + colb + 2 * hf) * 4;
    floatx16 acc = Z16;
    #pragma unroll
    for (int ky = 0; ky < 5; ++ky) {
      const f16* p = pA + ky * 224;
      half4 l0  = *(const half4*)(p);
      half4 h0  = *(const half4*)(p + 4);
      half4 l1  = *(const half4*)(p + 16);
      half4 h1v = *(const half4*)(p + 20);
      half8 a0v = __builtin_shufflevector(l0, h0, 0,1,2,3,4,5,6,7);
      half8 a1v = __builtin_shufflevector(l1, h1v, 0,1,2,3,4,5,6,7);
      acc = __builtin_amdgcn_mfma_f32_32x32x16_f16(a0v, B0[ky][0], acc, 0, 0, 0);
      acc = __builtin_amdgcn_mfma_f32_32x32x16_f16(a1v, B0[ky][1], acc, 0, 0, 0);
    }
    #pragma unroll
    for (int pp = 0; pp < 2; ++pp)
      #pragma unroll
      for (int c2 = 0; c2 < 2; ++c2) {
        float v = fmaxf(fmaxf(acc[8*pp + 2*c2], acc[8*pp + 2*c2 + 1]),
                        fmaxf(acc[8*pp + 4 + 2*c2], acc[8*pp + 4 + 2*c2 + 1]));
        v += b0c; v = (v >= 0.f) ? v : a0 * v;
        int pr = (r0 >> 1) + pp, pc = (cb >> 1) + 2 * hf + c2;
        if (pc < 21) s_h1[((pr + 1) * 26 + (pc + 1)) * 40 + col] = (f16)v;
      }
  }
  __syncthreads();   // conv0 done: s_x dead, s_h1 complete

  // zero s_h2 (aliases s_x region; pads must be 0)
  for (int i = tid; i < 2880; i += 512) smem_u[i] = 0u;
  __syncthreads();   // zeroing visible before conv1 epilogue writes

  // ---- conv1: 25 taps, K=32ci; 15 tiles32, 2 per wave; epilogue -> s_h2 ----
  const int r0lut1[5] = {0, 4, 8, 12, 14};
  const int cclut[3]  = {0, 8, 14};
  int t0 = wv * 2;
  int t1 = t0 + 1; if (t1 > 14) t1 = 14;
  int r0a = r0lut1[t0 / 3], cca = cclut[t0 % 3];
  int r0b = r0lut1[t1 / 3], ccb = cclut[t1 % 3];
  const f16* pAa = s_h1 + ((r0a + dr) * 26 + cca + dc) * 40 + hf * 8;
  const f16* pAb = s_h1 + ((r0b + dr) * 26 + ccb + dc) * 40 + hf * 8;
  floatx16 accA = Z16;
  floatx16 accB = Z16;
  for (int ky = 0; ky < 5; ++ky) {
    const half8* wb = w1t8 + ky * 640 + hf * 32 + col;
    const f16* qa = pAa + ky * 1040;
    const f16* qb = pAb + ky * 1040;
    #pragma unroll
    for (int kx = 0; kx < 5; ++kx) {
      #pragma unroll
      for (int ch = 0; ch < 2; ++ch) {
        half8 b  = wb[kx * 128 + ch * 64];
        half8 aA = *(const half8*)(qa + kx * 40 + ch * 16);
        half8 aB = *(const half8*)(qb + kx * 40 + ch * 16);
        accA = __builtin_amdgcn_mfma_f32_32x32x16_f16(aA, b, accA, 0, 0, 0);
        accB = __builtin_amdgcn_mfma_f32_32x32x16_f16(aB, b, accB, 0, 0, 0);
      }
    }
  }
  #pragma unroll
  for (int tt = 0; tt < 2; ++tt) {
    const floatx16 acc = tt ? accB : accA;
    int r0 = tt ? r0b : r0a, cc = tt ? ccb : cca;
    #pragma unroll
    for (int pp = 0; pp < 2; ++pp)
      #pragma unroll
      for (int c2 = 0; c2 < 2; ++c2) {
        float v = fmaxf(fmaxf(acc[8*pp + 2*c2], acc[8*pp + 2*c2 + 1]),
                        fmaxf(acc[8*pp + 4 + 2*c2], acc[8*pp + 4 + 2*c2 + 1]));
        v += b1c; v = (v >= 0.f) ? v : a1 * v;
        int pr = (r0 >> 1) + pp, pc = (cc >> 1) + 2 * hf + c2;
        if (pc < 9) s_h2[((pr + 1) * 12 + (pc + 1)) * 40 + col] = (f16)v;
      }
  }
  __syncthreads();   // s_h2 complete

  // ---- conv2: waves 0,1 (ct = wv); M = 8x8 pre-pool grid via 2 accs; K=512 ----
  if (wv < 2) {
    const int ct = wv;
    const float a2 = a2p[0];
    const float b2c = b2[ct * 32 + col];
    const f16* pA0 = s_h2 + (dr * 12 + dc) * 40 + hf * 8;
    const f16* pA4 = s_h2 + ((4 + dr) * 12 + dc) * 40 + hf * 8;
    floatx16 acc0 = Z16;
    floatx16 acc4 = Z16;
    for (int tap = 0; tap < 16; ++tap) {
      int ky = tap >> 2, kx = tap & 3;
      int aoff = (ky * 12 + kx) * 40;
      #pragma unroll
      for (int ch = 0; ch < 2; ++ch) {
        half8 b  = w2t8[tap * 256 + ch * 128 + ct * 64 + hf * 32 + col];
        half8 a0v = *(const half8*)(pA0 + aoff + ch * 16);
        half8 a4v = *(const half8*)(pA4 + aoff + ch * 16);
        acc0 = __builtin_amdgcn_mfma_f32_32x32x16_f16(a0v, b, acc0, 0, 0, 0);
        acc4 = __builtin_amdgcn_mfma_f32_32x32x16_f16(a4v, b, acc4, 0, 0, 0);
      }
    }
    f16* o = h3f + n * 1024;
    #pragma unroll
    for (int tt = 0; tt < 2; ++tt) {
      const floatx16 acc = tt ? acc4 : acc0;
      #pragma unroll
      for (int pp = 0; pp < 2; ++pp)
        #pragma unroll
        for (int c2 = 0; c2 < 2; ++c2) {
          float v = fmaxf(fmaxf(acc[8*pp + 2*c2], acc[8*pp + 2*c2 + 1]),
                          fmaxf(acc[8*pp + 4 + 2*c2], acc[8*pp + 4 + 2*c2 + 1]));
          v += b2c; v = (v >= 0.f) ? v : a2 * v;
          int pr = tt * 2 + pp, pc = 2 * hf + c2, co = ct * 32 + col;
          o[(pr * 4 + pc) * 64 + co] = (f16)v;
        }
    }
  }
}

// ---------------- fused conv3 + fc1 + fc2 + fc3 (MFMA f16) ----------------
// grid 96: blockIdx -> landmark l = b%6, image tile t = b/6 (32 images, n = (32t+i)*6+l)
__global__ __launch_bounds__(256) void k_tail(
    const f16* __restrict__ h3f,
    const f16* __restrict__ w3t, const float* __restrict__ b3, const float* __restrict__ a3p,
    const f16* __restrict__ fc1t, const float* __restrict__ fc1b, const float* __restrict__ a4,
    const f16* __restrict__ fc2t, const float* __restrict__ fc2b, const float* __restrict__ a5,
    const f16* __restrict__ fc3t, const float* __restrict__ fc3b,
    float* __restrict__ out)
{
  __shared__ __align__(16) f16 s_feat[32 * 264];
  __shared__ __align__(16) f16 s_g1[32 * 136];
  __shared__ __align__(16) f16 s_g2[32 * 72];

  const int lm = blockIdx.x % 6, t = blockIdx.x / 6;
  const int tid = threadIdx.x, wv = tid >> 6, lane = tid & 63;
  const int hf = lane >> 5, col = lane & 31;
  const half8* w3t8  = (const half8*)w3t;
  const half8* fc1t8 = (const half8*)fc1t;
  const half8* fc2t8 = (const half8*)fc2t;
  const half8* fc3t8 = (const half8*)fc3t;

  {
    const int mt = wv;
    const int i_img = mt * 8 + (col >> 2);
    const int pos = col & 3, oy = pos >> 1, ox = pos & 1;
    const int gimg = (t * 32 + i_img) * 6 + lm;
    const f16* Abase = h3f + gimg * 1024 + (oy * 4 + ox) * 64;
    floatx16 acc0 = Z16, acc1 = Z16;
    for (int c = 0; c < 36; ++c) {
      int tap = c >> 2;
      int ky = tap / 3, kx = tap % 3;
      half8 a = *(const half8*)(Abase + (ky * 4 + kx) * 64 + (c & 3) * 16 + hf * 8);
      half8 bb0 = w3t8[((c * 2 + 0) * 2 + hf) * 32 + col];
      half8 bb1 = w3t8[((c * 2 + 1) * 2 + hf) * 32 + col];
      acc0 = __builtin_amdgcn_mfma_f32_32x32x16_f16(a, bb0, acc0, 0, 0, 0);
      acc1 = __builtin_amdgcn_mfma_f32_32x32x16_f16(a, bb1, acc1, 0, 0, 0);
    }
    const float a3 = a3p[0];
    #pragma unroll
    for (int ct = 0; ct < 2; ++ct) {
      const floatx16 acc = ct ? acc1 : acc0;
      const int co = ct * 32 + col;
      const float bb = b3[co];
      #pragma unroll
      for (int q = 0; q < 4; ++q) {
        int ii = mt * 8 + 2 * q + hf;
        half4 w;
        #pragma unroll
        for (int z = 0; z < 4; ++z) {
          float v = acc[q * 4 + z] + bb;
          v = (v >= 0.f) ? v : a3 * v;
          w[z] = (f16)v;
        }
        *(half4*)(s_feat + ii * 264 + co * 4) = w;
      }
    }
  }
  __syncthreads();

  {
    floatx16 g = Z16;
    for (int c = 0; c < 16; ++c) {
      half8 a = *(const half8*)(s_feat + col * 264 + c * 16 + hf * 8);
      half8 b = fc1t8[(((lm * 16 + c) * 4 + wv) * 2 + hf) * 32 + col];
      g = __builtin_amdgcn_mfma_f32_32x32x16_f16(a, b, g, 0, 0, 0);
    }
    const float a4v = a4[lm];
    const float bb = fc1b[lm * 128 + wv * 32 + col];
    #pragma unroll
    for (int reg = 0; reg < 16; ++reg) {
      int r = (reg & 3) + 8 * (reg >> 2) + 4 * hf;
      float v = g[reg] + bb;
      v = (v >= 0.f) ? v : a4v * v;
      s_g1[r * 136 + wv * 32 + col] = (f16)v;
    }
  }
  __syncthreads();

  if (wv < 2) {
    floatx16 g = Z16;
    for (int c = 0; c < 8; ++c) {
      half8 a = *(const half8*)(s_g1 + col * 136 + c * 16 + hf * 8);
      half8 b = fc2t8[(((lm * 8 + c) * 2 + wv) * 2 + hf) * 32 + col];
      g = __builtin_amdgcn_mfma_f32_32x32x16_f16(a, b, g, 0, 0, 0);
    }
    const float a5v = a5[lm];
    const float bb = fc2b[lm * 64 + wv * 32 + col];
    #pragma unroll
    for (int reg = 0; reg < 16; ++reg) {
      int r = (reg & 3) + 8 * (reg >> 2) + 4 * hf;
      float v = g[reg] + bb;
      v = (v >= 0.f) ? v : a5v * v;
      s_g2[r * 72 + wv * 32 + col] = (f16)v;
    }
  }
  __syncthreads();

  if (wv == 0) {
    floatx16 g = Z16;
    for (int c = 0; c < 4; ++c) {
      half8 a = *(const half8*)(s_g2 + col * 72 + c * 16 + hf * 8);
      half8 b = fc3t8[((lm * 4 + c) * 2 + hf) * 32 + col];
      g = __builtin_amdgcn_mfma_f32_32x32x16_f16(a, b, g, 0, 0, 0);
    }
    if (col < 4) {
      const float bb = fc3b[lm * 4 + col];
      #pragma unroll
      for (int reg = 0; reg < 16; ++reg) {
        int r = (reg & 3) + 8 * (reg >> 2) + 4 * hf;
        out[((t * 32 + r) * 6 + lm) * 4 + col] = g[reg] + bb;
      }
    }
  }
}

extern "C" void kernel_launch(void* const* d_in, const int* in_sizes, int n_in,
                              void* d_out, int out_size, void* d_ws, size_t ws_size,
                              hipStream_t stream) {
  const float* x    = (const float*)d_in[0];
  const float* w0   = (const float*)d_in[1];
  const float* b0   = (const float*)d_in[2];
  const float* w1   = (const float*)d_in[3];
  const float* b1   = (const float*)d_in[4];
  const float* w2   = (const float*)d_in[5];
  const float* b2   = (const float*)d_in[6];
  const float* w3   = (const float*)d_in[7];
  const float* b3   = (const float*)d_in[8];
  const float* a0   = (const float*)d_in[9];
  const float* a1   = (const float*)d_in[10];
  const float* a2   = (const float*)d_in[11];
  const float* a3   = (const float*)d_in[12];
  const float* fc1w = (const float*)d_in[13];
  const float* fc1b = (const float*)d_in[14];
  const float* a4   = (const float*)d_in[15];
  const float* fc2w = (const float*)d_in[16];
  const float* fc2b = (const float*)d_in[17];
  const float* a5   = (const float*)d_in[18];
  const float* fc3w = (const float*)d_in[19];
  const float* fc3b = (const float*)d_in[20];
  float* out = (float*)d_out;

  char* ws = (char*)d_ws;
  f16* w0t  = (f16*)(ws + WS_W0T);
  f16* w1t  = (f16*)(ws + WS_W1T);
  f16* w2t  = (f16*)(ws + WS_W2T);
  f16* w3t  = (f16*)(ws + WS_W3T);
  f16* fc1t = (f16*)(ws + WS_FC1T);
  f16* fc2t = (f16*)(ws + WS_FC2T);
  f16* fc3t = (f16*)(ws + WS_FC3T);
  f16* h3f  = (f16*)(ws + WS_H3F);

  k_prep   <<<128, 256, 0, stream>>>(w0, w1, w2, w3, fc1w, fc2w, fc3w,
                                     w0t, w1t, w2t, w3t, fc1t, fc2t, fc3t);
  k_conv012<<<NIMG, 512, 0, stream>>>(x, w0t, b0, a0, w1t, b1, a1, w2t, b2, a2, h3f);
  k_tail   <<<96, 256, 0, stream>>>(h3f, w3t, b3, a3, fc1t, fc1b, a4,
                                    fc2t, fc2b, a5, fc3t, fc3b, out);
}